// Round 1
// 439.302 us; speedup vs baseline: 2.7228x; 2.7228x over previous
//
#include <hip/hip_runtime.h>
#include <hip/hip_bf16.h>
#include <math.h>

typedef __hip_bfloat16 hbf16;
typedef __attribute__((ext_vector_type(8))) short short8;   // 8 bf16 (4 VGPRs)
typedef __attribute__((ext_vector_type(4))) float f32x4;

static const long QS = 2097152;  // 512*4096 per-batch q/k/v/out elems

__device__ __forceinline__ unsigned short f2bf(float f) {
    hbf16 h = __float2bfloat16(f);
    return *reinterpret_cast<unsigned short*>(&h);
}
__device__ __forceinline__ float bf2f(unsigned short u) {
    unsigned x = ((unsigned)u) << 16;
    return __uint_as_float(x);
}
__device__ __forceinline__ unsigned pk2(float a, float b) {
    return (unsigned)f2bf(a) | ((unsigned)f2bf(b) << 16);
}

// async 16-B global->LDS (wave-uniform LDS base + lane*16)
__device__ __forceinline__ void gload16(const void* g, void* l) {
    __builtin_amdgcn_global_load_lds(
        (const __attribute__((address_space(1))) void*)g,
        (__attribute__((address_space(3))) void*)l, 16, 0, 0);
}

// Stage R rows x 32 k (bf16) from global P (row0*ld + koff addressing) into Ls.
// LDS slot s of row r holds global k-chunk (s ^ (r&3))  [xor swizzle].
template <int R>
__device__ __forceinline__ void stage_direct(const short* P, int ld, int row0,
                                             long koff, short* Ls) {
    const int tid = threadIdx.x;
    const int w = tid >> 6, lane = tid & 63;
#pragma unroll
    for (int j = 0; j < R / 64; ++j) {
        int rb = j * 64 + w * 16;
        int r = rb + (lane >> 2);
        int s = lane & 3;
        int g = s ^ (r & 3);
        const short* ga = P + (long)(row0 + r) * ld + koff + g * 8;
        gload16(ga, Ls + rb * 32);
    }
}

// Stage R rows x 32 k from fp32 source X where operand[r][k] = X[(k0+k)*sld + row0+r]
// (transpose+cast in VGPRs, ds_write_b128, same xor swizzle).
template <int R>
__device__ __forceinline__ void stage_trans(const float* X, int sld, int row0,
                                            int k0, short* Ls) {
    const int tid = threadIdx.x;
    constexpr int L2R = (R == 128) ? 7 : 6;
#pragma unroll
    for (int j = 0; j < R / 64; ++j) {
        int idx = j * 256 + tid;
        int r = idx & (R - 1);
        int c = idx >> L2R;
        long base = (long)(k0 + c * 8) * sld + row0 + r;
        float f[8];
#pragma unroll
        for (int jj = 0; jj < 8; ++jj) f[jj] = X[base + (long)jj * sld];
        uint4 pkv;
        pkv.x = pk2(f[0], f[1]);
        pkv.y = pk2(f[2], f[3]);
        pkv.z = pk2(f[4], f[5]);
        pkv.w = pk2(f[6], f[7]);
        int s = c ^ (r & 3);
        *reinterpret_cast<uint4*>(Ls + r * 32 + s * 8) = pkv;
    }
}

#define EPI_BF 0   // bf16 C[row][col], ldc
#define EPI_YT 1   // AV: scatter to YtvT[4096][256]
#define EPI_OUT 2  // fp32 out + q + v residual, ldc=4096

// Generic NT MFMA GEMM: C[m][n] = sum_k A[m][k]*B[n][k], tile TM x TN, BK=32.
// DIRECT operands: bf16, element addr = row*ld + (k&kmask) + (k>>kshift)*kpanel.
// TRANS operands: fp32 X, element = X[k*sld + row]  (in-kernel transpose+cast).
// blockIdx.z = batch within group; bsA/bsB/bsC/bsR are per-batch element strides.
template <int TM, int TN, bool TRA, bool TRB, int EPI>
__global__ __launch_bounds__(256) void mm(
    const short* __restrict__ A, const float* __restrict__ Af,
    const short* __restrict__ B, const float* __restrict__ Bf,
    void* __restrict__ C, const float* __restrict__ Rq, const float* __restrict__ Rv,
    int K, int lda, int ldb, int ldc, int kmask, int kshift, long kpanel,
    long bsA, long bsB, long bsC, long bsR)
{
    __shared__ __align__(16) short As[TM * 32];
    __shared__ __align__(16) short Bs[TN * 32];

    const int tid = threadIdx.x;
    const int w = tid >> 6, lane = tid & 63;
    const int quad = lane >> 4, l16 = lane & 15;
    const int m0 = blockIdx.y * TM;
    const int n0 = blockIdx.x * TN;
    const int bz = blockIdx.z;

    if constexpr (TRA) Af += (long)bz * bsA; else A += (long)bz * bsA;
    if constexpr (TRB) Bf += (long)bz * bsB; else B += (long)bz * bsB;
    const long cb = (long)bz * bsC;
    if constexpr (EPI == EPI_OUT) { Rq += (long)bz * bsR; Rv += (long)bz * bsR; }

    constexpr int WM = TM / 2;      // wave rows
    constexpr int MT = WM / 16;     // mfma tiles per wave (rows)
    const int wm = (w & 1) * WM;
    const int wn = (w >> 1) * 64;

    f32x4 acc[MT][4];
#pragma unroll
    for (int i = 0; i < MT; ++i)
#pragma unroll
        for (int j = 0; j < 4; ++j) acc[i][j] = (f32x4){0.f, 0.f, 0.f, 0.f};

    for (int k0 = 0; k0 < K; k0 += 32) {
        __syncthreads();
        long koff = (long)(k0 & kmask) + (long)(k0 >> kshift) * kpanel;
        if constexpr (TRA) stage_trans<TM>(Af, lda, m0, k0, As);
        else               stage_direct<TM>(A, lda, m0, koff, As);
        if constexpr (TRB) stage_trans<TN>(Bf, ldb, n0, k0, Bs);
        else               stage_direct<TN>(B, ldb, n0, koff, Bs);
        __syncthreads();

        short8 af[MT], bfr[4];
#pragma unroll
        for (int mt = 0; mt < MT; ++mt) {
            int r = wm + mt * 16 + l16;
            int s = quad ^ (r & 3);
            af[mt] = *reinterpret_cast<const short8*>(&As[r * 32 + s * 8]);
        }
#pragma unroll
        for (int nt = 0; nt < 4; ++nt) {
            int r = wn + nt * 16 + l16;
            int s = quad ^ (r & 3);
            bfr[nt] = *reinterpret_cast<const short8*>(&Bs[r * 32 + s * 8]);
        }
#pragma unroll
        for (int mt = 0; mt < MT; ++mt)
#pragma unroll
            for (int nt = 0; nt < 4; ++nt)
                acc[mt][nt] = __builtin_amdgcn_mfma_f32_16x16x32_bf16(
                    af[mt], bfr[nt], acc[mt][nt], 0, 0, 0);
    }

    // Epilogue. C/D layout: col = lane&15, row = quad*4 + reg.
#pragma unroll
    for (int mt = 0; mt < MT; ++mt)
#pragma unroll
        for (int nt = 0; nt < 4; ++nt)
#pragma unroll
            for (int reg = 0; reg < 4; ++reg) {
                int gr = m0 + wm + mt * 16 + quad * 4 + reg;
                int gc = n0 + wn + nt * 16 + l16;
                float vacc = acc[mt][nt][reg];
                if constexpr (EPI == EPI_BF) {
                    ((short*)C)[cb + (long)gr * ldc + gc] = (short)f2bf(vacc);
                } else if constexpr (EPI == EPI_YT) {
                    long a = (long)gc * 256 + (long)(gr & 1) * 524288 + (gr >> 1);
                    ((short*)C)[cb + a] = (short)f2bf(vacc);
                } else {
                    long a = (long)gr * 4096 + gc;
                    ((float*)C)[cb + a] = vacc + Rq[a] + Rv[a];
                }
            }
}

// Row softmax of T[nrows][2048] bf16 in place (one block per row).
// Batches are contiguous, so a flat row index spans the whole group.
__global__ __launch_bounds__(256) void softmax_row(short* __restrict__ T) {
    const int row = blockIdx.x;
    const int tid = threadIdx.x;
    const int w = tid >> 6, lane = tid & 63;
    __shared__ float red[8];

    uint4 u = *reinterpret_cast<const uint4*>(&T[(long)row * 2048 + tid * 8]);
    float f[8];
    f[0] = bf2f((unsigned short)(u.x & 0xffff)); f[1] = bf2f((unsigned short)(u.x >> 16));
    f[2] = bf2f((unsigned short)(u.y & 0xffff)); f[3] = bf2f((unsigned short)(u.y >> 16));
    f[4] = bf2f((unsigned short)(u.z & 0xffff)); f[5] = bf2f((unsigned short)(u.z >> 16));
    f[6] = bf2f((unsigned short)(u.w & 0xffff)); f[7] = bf2f((unsigned short)(u.w >> 16));

    float m = f[0];
#pragma unroll
    for (int j = 1; j < 8; ++j) m = fmaxf(m, f[j]);
    for (int o = 32; o > 0; o >>= 1) m = fmaxf(m, __shfl_down(m, o));
    if (lane == 0) red[w] = m;
    __syncthreads();
    float M = fmaxf(fmaxf(red[0], red[1]), fmaxf(red[2], red[3]));

    float e[8], s = 0.f;
#pragma unroll
    for (int j = 0; j < 8; ++j) { e[j] = __expf(f[j] - M); s += e[j]; }
    for (int o = 32; o > 0; o >>= 1) s += __shfl_down(s, o);
    if (lane == 0) red[4 + w] = s;
    __syncthreads();
    float invL = 1.0f / (red[4] + red[5] + red[6] + red[7]);

    uint4 ov;
    ov.x = pk2(e[0] * invL, e[1] * invL);
    ov.y = pk2(e[2] * invL, e[3] * invL);
    ov.z = pk2(e[4] * invL, e[5] * invL);
    ov.w = pk2(e[6] * invL, e[7] * invL);
    *reinterpret_cast<uint4*>(&T[(long)row * 2048 + tid * 8]) = ov;
}

// Cast 4 weight matrices (131072 fp32 each) to bf16, concatenated into W.
__global__ __launch_bounds__(256) void cast_w(
    const float* __restrict__ a, const float* __restrict__ b,
    const float* __restrict__ c, const float* __restrict__ d,
    short* __restrict__ W)
{
    const float* S[4] = {a, b, c, d};
    int sel = blockIdx.y;
    int i = (blockIdx.x * 256 + threadIdx.x) * 4;
    float4 f = *reinterpret_cast<const float4*>(&S[sel][i]);
    uint2 o;
    o.x = pk2(f.x, f.y);
    o.y = pk2(f.z, f.w);
    *reinterpret_cast<uint2*>(&W[sel * 131072 + i]) = o;
}

extern "C" void kernel_launch(void* const* d_in, const int* in_sizes, int n_in,
                              void* d_out, int out_size, void* d_ws, size_t ws_size,
                              hipStream_t stream)
{
    const float* q    = (const float*)d_in[0];
    const float* kk   = (const float*)d_in[1];
    const float* v    = (const float*)d_in[2];
    const float* Wphi = (const float*)d_in[3];
    const float* Wth  = (const float*)d_in[4];
    const float* Wg   = (const float*)d_in[5];
    const float* Wm   = (const float*)d_in[6];
    float* out = (float*)d_out;
    dim3 blk(256);

    // Per-batch workspace (shorts): Phi 1M | Th 1M | Gr 1M | T 4M | YtvT 1M = 8M shorts
    const long PB = 8388608;
    long ws_shorts = (long)(ws_size / 2);
    int NB = (int)((ws_shorts - 524288) / PB);
    if (NB > 8) NB = 8;
    if (NB < 1) NB = 1;   // previous kernel's 17 MB footprint == NB=1 case

    short* Wb   = (short*)d_ws;              // 512K shorts
    short* Phi  = Wb + 524288;               // [NB][4096][256] = phi^T (conv-T output)
    short* Th   = Phi + (long)NB * 1048576;  // [NB][4096][256]
    short* Gr   = Th + (long)NB * 1048576;   // [NB][256][4096] (flat == G[512][2048])
    short* T    = Gr + (long)NB * 1048576;   // [NB][2048][2048] = S^T, then attn^T
    short* YtvT = T + (long)NB * 4194304;    // [NB][4096][256]
    const short* WbPhi = Wb;
    const short* WbTh  = Wb + 131072;
    const short* WbG   = Wb + 262144;
    const short* WbM   = Wb + 393216;

    const int LIN_M = 0x3FFFFFFF, LIN_S = 30;  // linear k addressing

    cast_w<<<dim3(128, 4), blk, 0, stream>>>(Wphi, Wth, Wg, Wm, Wb);

    for (int b0 = 0; b0 < 8; b0 += NB) {
        int nb = 8 - b0 < NB ? 8 - b0 : NB;
        const float* qb = q + (long)b0 * QS;
        const float* kb = kk + (long)b0 * QS;
        const float* vb = v + (long)b0 * QS;

        // conv-T: Phi[p][o] = sum_c q[c][p] * Wphi[o][c]   (M=4096, N=256, K=512)
        mm<128, 128, true, false, EPI_BF><<<dim3(2, 32, nb), blk, 0, stream>>>(
            nullptr, qb, WbPhi, nullptr, Phi, nullptr, nullptr,
            512, 4096, 512, 256, LIN_M, LIN_S, 0,
            QS, 0, 1048576, 0);
        mm<128, 128, true, false, EPI_BF><<<dim3(2, 32, nb), blk, 0, stream>>>(
            nullptr, kb, WbTh, nullptr, Th, nullptr, nullptr,
            512, 4096, 512, 256, LIN_M, LIN_S, 0,
            QS, 0, 1048576, 0);
        // conv-N: Gr[o][p] = sum_c Wg[o][c] * v[c][p]      (M=256, N=4096, K=512)
        mm<128, 128, false, true, EPI_BF><<<dim3(32, 2, nb), blk, 0, stream>>>(
            WbG, nullptr, nullptr, vb, Gr, nullptr, nullptr,
            512, 512, 4096, 4096, LIN_M, LIN_S, 0,
            0, QS, 1048576, 0);

        // score: T[m][n] = S^T = sum_{h,o} Phi[h*2048+m][o]*Th[h*2048+n][o]
        // k-panel: kmask=255, kshift=8, kpanel=2048*256  (M=N=2048, K=512)
        mm<128, 128, false, false, EPI_BF><<<dim3(16, 16, nb), blk, 0, stream>>>(
            Phi, nullptr, Th, nullptr, T, nullptr, nullptr,
            512, 256, 256, 2048, 255, 8, 524288,
            1048576, 1048576, 4194304, 0);

        softmax_row<<<dim3(2048 * nb), blk, 0, stream>>>(T);

        // AV: Yt[c'][m] = sum_n Gflat[c'][n] * T[m][n]  (M=512, N=2048, K=2048)
        // epilogue scatters to YtvT[4096][256]
        mm<64, 128, false, false, EPI_YT><<<dim3(16, 8, nb), blk, 0, stream>>>(
            Gr, nullptr, T, nullptr, YtvT, nullptr, nullptr,
            2048, 2048, 2048, 256, LIN_M, LIN_S, 0,
            1048576, 4194304, 1048576, 0);

        // mask + residual: out[o][p] = sum_i WbM[o][i]*YtvT[p][i] + q + v
        // (M=512, N=4096, K=256)
        mm<128, 128, false, false, EPI_OUT><<<dim3(32, 4, nb), blk, 0, stream>>>(
            WbM, nullptr, YtvT, nullptr, out + (long)b0 * QS, qb, vb,
            256, 256, 256, 4096, LIN_M, LIN_S, 0,
            0, 1048576, QS, QS);
    }
}

// Round 2
// 424.852 us; speedup vs baseline: 2.8154x; 1.0340x over previous
//
#include <hip/hip_runtime.h>
#include <hip/hip_bf16.h>
#include <math.h>

typedef __hip_bfloat16 hbf16;
typedef __attribute__((ext_vector_type(8))) short short8;   // 8 bf16 (4 VGPRs)
typedef __attribute__((ext_vector_type(4))) float f32x4;

static const long QS = 2097152;  // 512*4096 per-batch q/k/v/out elems

__device__ __forceinline__ unsigned short f2bf(float f) {
    hbf16 h = __float2bfloat16(f);
    return *reinterpret_cast<unsigned short*>(&h);
}
__device__ __forceinline__ float bf2f(unsigned short u) {
    unsigned x = ((unsigned)u) << 16;
    return __uint_as_float(x);
}
__device__ __forceinline__ unsigned pk2(float a, float b) {
    return (unsigned)f2bf(a) | ((unsigned)f2bf(b) << 16);
}

// async 16-B global->LDS (wave-uniform LDS base + lane*16)
__device__ __forceinline__ void gload16(const void* g, void* l) {
    __builtin_amdgcn_global_load_lds(
        (const __attribute__((address_space(1))) void*)g,
        (__attribute__((address_space(3))) void*)l, 16, 0, 0);
}

// BK=64 staging. LDS row r = 64 shorts (128 B) = 8 chunk slots of 8 shorts.
// Slot s of row r holds global k-chunk (s ^ (r&7))  [xor swizzle, period 8 ->
// ds_read_b128 lands 2-way per bank group = free].
// Each 8-lane group of a gload16 issue fetches one contiguous 128-B row.
template <int R>
__device__ __forceinline__ void stage_direct(const short* P, int ld, int row0,
                                             long koff, short* Ls) {
    const int tid = threadIdx.x;
    const int w = tid >> 6, lane = tid & 63;
    const int lrow = lane >> 3;   // 0..7 row within 8-row issue
    const int s = lane & 7;       // LDS slot
#pragma unroll
    for (int j = 0; j < R / 32; ++j) {
        int rowbase = w * (R / 4) + j * 8;
        int r = rowbase + lrow;
        int g = s ^ (r & 7);      // global chunk fetched into slot s
        const short* ga = P + (long)(row0 + r) * ld + koff + g * 8;
        gload16(ga, Ls + rowbase * 64);
    }
}

// Stage R rows x 64 k from fp32 source X where operand[r][k] = X[(k0+k)*sld + row0+r]
// (transpose+cast in VGPRs, ds_write_b128, same xor swizzle).
template <int R>
__device__ __forceinline__ void stage_trans(const float* X, int sld, int row0,
                                            int k0, short* Ls) {
    const int tid = threadIdx.x;
    constexpr int L2R = (R == 128) ? 7 : 6;
#pragma unroll
    for (int j = 0; j < R / 32; ++j) {
        int idx = j * 256 + tid;
        int r = idx & (R - 1);
        int c = idx >> L2R;       // chunk 0..7
        long base = (long)(k0 + c * 8) * sld + row0 + r;
        float f[8];
#pragma unroll
        for (int jj = 0; jj < 8; ++jj) f[jj] = X[base + (long)jj * sld];
        uint4 pkv;
        pkv.x = pk2(f[0], f[1]);
        pkv.y = pk2(f[2], f[3]);
        pkv.z = pk2(f[4], f[5]);
        pkv.w = pk2(f[6], f[7]);
        int s = c ^ (r & 7);
        *reinterpret_cast<uint4*>(Ls + r * 64 + s * 8) = pkv;
    }
}

#define EPI_BF 0   // bf16 C[row][col], ldc
#define EPI_YT 1   // AV: scatter to YtvT[4096][256]
#define EPI_OUT 2  // fp32 out + q + v residual, ldc=4096

// Generic NT MFMA GEMM: C[m][n] = sum_k A[m][k]*B[n][k], tile TM x TN, BK=64.
// DIRECT operands: bf16, element addr = row*ld + (k&kmask) + (k>>kshift)*kpanel.
// TRANS operands: fp32 X, element = X[k*sld + row]  (in-kernel transpose+cast).
// blockIdx.z = batch within group; bsA/bsB/bsC/bsR are per-batch element strides.
template <int TM, int TN, bool TRA, bool TRB, int EPI>
__global__ __launch_bounds__(256) void mm(
    const short* __restrict__ A, const float* __restrict__ Af,
    const short* __restrict__ B, const float* __restrict__ Bf,
    void* __restrict__ C, const float* __restrict__ Rq, const float* __restrict__ Rv,
    int K, int lda, int ldb, int ldc, int kmask, int kshift, long kpanel,
    long bsA, long bsB, long bsC, long bsR)
{
    __shared__ __align__(16) short As[TM * 64];
    __shared__ __align__(16) short Bs[TN * 64];

    const int tid = threadIdx.x;
    const int w = tid >> 6, lane = tid & 63;
    const int quad = lane >> 4, l16 = lane & 15;
    const int m0 = blockIdx.y * TM;
    const int n0 = blockIdx.x * TN;
    const int bz = blockIdx.z;

    if constexpr (TRA) Af += (long)bz * bsA; else A += (long)bz * bsA;
    if constexpr (TRB) Bf += (long)bz * bsB; else B += (long)bz * bsB;
    const long cb = (long)bz * bsC;
    if constexpr (EPI == EPI_OUT) { Rq += (long)bz * bsR; Rv += (long)bz * bsR; }

    constexpr int WM = TM / 2;      // wave rows
    constexpr int MT = WM / 16;     // mfma tiles per wave (rows)
    const int wm = (w & 1) * WM;
    const int wn = (w >> 1) * 64;

    f32x4 acc[MT][4];
#pragma unroll
    for (int i = 0; i < MT; ++i)
#pragma unroll
        for (int j = 0; j < 4; ++j) acc[i][j] = (f32x4){0.f, 0.f, 0.f, 0.f};

    for (int k0 = 0; k0 < K; k0 += 64) {
        __syncthreads();
        long koff = (long)(k0 & kmask) + (long)(k0 >> kshift) * kpanel;
        if constexpr (TRA) stage_trans<TM>(Af, lda, m0, k0, As);
        else               stage_direct<TM>(A, lda, m0, koff, As);
        if constexpr (TRB) stage_trans<TN>(Bf, ldb, n0, k0, Bs);
        else               stage_direct<TN>(B, ldb, n0, koff, Bs);
        __syncthreads();

#pragma unroll
        for (int ks = 0; ks < 2; ++ks) {
            short8 af[MT], bfr[4];
#pragma unroll
            for (int mt = 0; mt < MT; ++mt) {
                int r = wm + mt * 16 + l16;
                int s = (ks * 4 + quad) ^ (r & 7);
                af[mt] = *reinterpret_cast<const short8*>(&As[r * 64 + s * 8]);
            }
#pragma unroll
            for (int nt = 0; nt < 4; ++nt) {
                int r = wn + nt * 16 + l16;
                int s = (ks * 4 + quad) ^ (r & 7);
                bfr[nt] = *reinterpret_cast<const short8*>(&Bs[r * 64 + s * 8]);
            }
#pragma unroll
            for (int mt = 0; mt < MT; ++mt)
#pragma unroll
                for (int nt = 0; nt < 4; ++nt)
                    acc[mt][nt] = __builtin_amdgcn_mfma_f32_16x16x32_bf16(
                        af[mt], bfr[nt], acc[mt][nt], 0, 0, 0);
        }
    }

    // Epilogue. C/D layout: col = lane&15, row = quad*4 + reg.
#pragma unroll
    for (int mt = 0; mt < MT; ++mt)
#pragma unroll
        for (int nt = 0; nt < 4; ++nt)
#pragma unroll
            for (int reg = 0; reg < 4; ++reg) {
                int gr = m0 + wm + mt * 16 + quad * 4 + reg;
                int gc = n0 + wn + nt * 16 + l16;
                float vacc = acc[mt][nt][reg];
                if constexpr (EPI == EPI_BF) {
                    ((short*)C)[cb + (long)gr * ldc + gc] = (short)f2bf(vacc);
                } else if constexpr (EPI == EPI_YT) {
                    long a = (long)gc * 256 + (long)(gr & 1) * 524288 + (gr >> 1);
                    ((short*)C)[cb + a] = (short)f2bf(vacc);
                } else {
                    long a = (long)gr * 4096 + gc;
                    ((float*)C)[cb + a] = vacc + Rq[a] + Rv[a];
                }
            }
}

// Row softmax of T[nrows][2048] bf16 in place (one block per row).
// Batches are contiguous, so a flat row index spans the whole group.
__global__ __launch_bounds__(256) void softmax_row(short* __restrict__ T) {
    const int row = blockIdx.x;
    const int tid = threadIdx.x;
    const int w = tid >> 6, lane = tid & 63;
    __shared__ float red[8];

    uint4 u = *reinterpret_cast<const uint4*>(&T[(long)row * 2048 + tid * 8]);
    float f[8];
    f[0] = bf2f((unsigned short)(u.x & 0xffff)); f[1] = bf2f((unsigned short)(u.x >> 16));
    f[2] = bf2f((unsigned short)(u.y & 0xffff)); f[3] = bf2f((unsigned short)(u.y >> 16));
    f[4] = bf2f((unsigned short)(u.z & 0xffff)); f[5] = bf2f((unsigned short)(u.z >> 16));
    f[6] = bf2f((unsigned short)(u.w & 0xffff)); f[7] = bf2f((unsigned short)(u.w >> 16));

    float m = f[0];
#pragma unroll
    for (int j = 1; j < 8; ++j) m = fmaxf(m, f[j]);
    for (int o = 32; o > 0; o >>= 1) m = fmaxf(m, __shfl_down(m, o));
    if (lane == 0) red[w] = m;
    __syncthreads();
    float M = fmaxf(fmaxf(red[0], red[1]), fmaxf(red[2], red[3]));

    float e[8], s = 0.f;
#pragma unroll
    for (int j = 0; j < 8; ++j) { e[j] = __expf(f[j] - M); s += e[j]; }
    for (int o = 32; o > 0; o >>= 1) s += __shfl_down(s, o);
    if (lane == 0) red[4 + w] = s;
    __syncthreads();
    float invL = 1.0f / (red[4] + red[5] + red[6] + red[7]);

    uint4 ov;
    ov.x = pk2(e[0] * invL, e[1] * invL);
    ov.y = pk2(e[2] * invL, e[3] * invL);
    ov.z = pk2(e[4] * invL, e[5] * invL);
    ov.w = pk2(e[6] * invL, e[7] * invL);
    *reinterpret_cast<uint4*>(&T[(long)row * 2048 + tid * 8]) = ov;
}

// Cast 4 weight matrices (131072 fp32 each) to bf16, concatenated into W.
__global__ __launch_bounds__(256) void cast_w(
    const float* __restrict__ a, const float* __restrict__ b,
    const float* __restrict__ c, const float* __restrict__ d,
    short* __restrict__ W)
{
    const float* S[4] = {a, b, c, d};
    int sel = blockIdx.y;
    int i = (blockIdx.x * 256 + threadIdx.x) * 4;
    float4 f = *reinterpret_cast<const float4*>(&S[sel][i]);
    uint2 o;
    o.x = pk2(f.x, f.y);
    o.y = pk2(f.z, f.w);
    *reinterpret_cast<uint2*>(&W[sel * 131072 + i]) = o;
}

extern "C" void kernel_launch(void* const* d_in, const int* in_sizes, int n_in,
                              void* d_out, int out_size, void* d_ws, size_t ws_size,
                              hipStream_t stream)
{
    const float* q    = (const float*)d_in[0];
    const float* kk   = (const float*)d_in[1];
    const float* v    = (const float*)d_in[2];
    const float* Wphi = (const float*)d_in[3];
    const float* Wth  = (const float*)d_in[4];
    const float* Wg   = (const float*)d_in[5];
    const float* Wm   = (const float*)d_in[6];
    float* out = (float*)d_out;
    dim3 blk(256);

    // Per-batch workspace (shorts): Phi 1M | Th 1M | Gr 1M | T 4M | YtvT 1M = 8M shorts
    const long PB = 8388608;
    long ws_shorts = (long)(ws_size / 2);
    int NB = (int)((ws_shorts - 524288) / PB);
    if (NB > 8) NB = 8;
    if (NB < 1) NB = 1;

    short* Wb   = (short*)d_ws;              // 512K shorts
    short* Phi  = Wb + 524288;               // [NB][4096][256] = phi^T (conv-T output)
    short* Th   = Phi + (long)NB * 1048576;  // [NB][4096][256]
    short* Gr   = Th + (long)NB * 1048576;   // [NB][256][4096] (flat == G[512][2048])
    short* T    = Gr + (long)NB * 1048576;   // [NB][2048][2048] = S^T, then attn^T
    short* YtvT = T + (long)NB * 4194304;    // [NB][4096][256]
    const short* WbPhi = Wb;
    const short* WbTh  = Wb + 131072;
    const short* WbG   = Wb + 262144;
    const short* WbM   = Wb + 393216;

    const int LIN_M = 0x3FFFFFFF, LIN_S = 30;  // linear k addressing

    cast_w<<<dim3(128, 4), blk, 0, stream>>>(Wphi, Wth, Wg, Wm, Wb);

    for (int b0 = 0; b0 < 8; b0 += NB) {
        int nb = 8 - b0 < NB ? 8 - b0 : NB;
        const float* qb = q + (long)b0 * QS;
        const float* kb = kk + (long)b0 * QS;
        const float* vb = v + (long)b0 * QS;

        // conv-T: Phi[p][o] = sum_c q[c][p] * Wphi[o][c]   (M=4096, N=256, K=512)
        mm<128, 128, true, false, EPI_BF><<<dim3(2, 32, nb), blk, 0, stream>>>(
            nullptr, qb, WbPhi, nullptr, Phi, nullptr, nullptr,
            512, 4096, 512, 256, LIN_M, LIN_S, 0,
            QS, 0, 1048576, 0);
        mm<128, 128, true, false, EPI_BF><<<dim3(2, 32, nb), blk, 0, stream>>>(
            nullptr, kb, WbTh, nullptr, Th, nullptr, nullptr,
            512, 4096, 512, 256, LIN_M, LIN_S, 0,
            QS, 0, 1048576, 0);
        // conv-N: Gr[o][p] = sum_c Wg[o][c] * v[c][p]      (M=256, N=4096, K=512)
        mm<128, 128, false, true, EPI_BF><<<dim3(32, 2, nb), blk, 0, stream>>>(
            WbG, nullptr, nullptr, vb, Gr, nullptr, nullptr,
            512, 512, 4096, 4096, LIN_M, LIN_S, 0,
            0, QS, 1048576, 0);

        // score: T[m][n] = S^T = sum_{h,o} Phi[h*2048+m][o]*Th[h*2048+n][o]
        // k-panel: kmask=255, kshift=8, kpanel=2048*256  (M=N=2048, K=512)
        mm<128, 128, false, false, EPI_BF><<<dim3(16, 16, nb), blk, 0, stream>>>(
            Phi, nullptr, Th, nullptr, T, nullptr, nullptr,
            512, 256, 256, 2048, 255, 8, 524288,
            1048576, 1048576, 4194304, 0);

        softmax_row<<<dim3(2048 * nb), blk, 0, stream>>>(T);

        // AV: Yt[c'][m] = sum_n Gflat[c'][n] * T[m][n]  (M=512, N=2048, K=2048)
        // epilogue scatters to YtvT[4096][256]
        mm<64, 128, false, false, EPI_YT><<<dim3(16, 8, nb), blk, 0, stream>>>(
            Gr, nullptr, T, nullptr, YtvT, nullptr, nullptr,
            2048, 2048, 2048, 256, LIN_M, LIN_S, 0,
            1048576, 4194304, 1048576, 0);

        // mask + residual: out[o][p] = sum_i WbM[o][i]*YtvT[p][i] + q + v
        // (M=512, N=4096, K=256)
        mm<128, 128, false, false, EPI_OUT><<<dim3(32, 4, nb), blk, 0, stream>>>(
            WbM, nullptr, YtvT, nullptr, out + (long)b0 * QS, qb, vb,
            256, 256, 256, 4096, LIN_M, LIN_S, 0,
            0, 1048576, QS, QS);
    }
}